// Round 13
// baseline (443.474 us; speedup 1.0000x reference)
//
#include <hip/hip_runtime.h>
#include <math.h>

// ---------------------------------------------------------------------------
// GCN 3-layer inference. bf16 data path, fp32 accumulation.
// KEY IDEA (R12): feature-tiled intermediate layout Xt[chunk][node][16] with
// chunk = blockIdx&7 -> XCD-affine gather; each XCD's 3.2MB slice is
// L2-resident, converting the 8x cross-XCD re-fetch into L2 hits.
//   CSR build: LDS-multisplit radix partition
//   k_gemmN<AFP32,ATILED,NCT,OTILED>: MFMA 16x16x32 bf16, LDS-free
//   k_agg128t: tiled gather (4 lanes/node), nt col loads, fused BN+ReLU
//   k_agg40: bf16 row-major gather + bias + log_softmax
// Pipeline: gemm0(x@W0)->XsA_t; agg128t->XsB_t; gemm1->XsA_t; agg128t->XsB_t;
//           gemm2(W2,NCT=3,row-major out)->bufC; agg40->out
// ---------------------------------------------------------------------------

#define CSHIFT 9
#define CSZ 512
#define PCHUNK 4096

typedef unsigned short u16;
typedef unsigned int u32;
typedef unsigned char u8;
typedef float f32x4 __attribute__((ext_vector_type(4)));
typedef short s16x8 __attribute__((ext_vector_type(8)));
typedef unsigned int u32x2 __attribute__((ext_vector_type(2)));

__device__ inline float bflo(u32 u) { return __uint_as_float(u << 16); }
__device__ inline float bfhi(u32 u) { return __uint_as_float(u & 0xffff0000u); }
__device__ inline u16 f2bf(float f) {  // RNE
    u32 b = __float_as_uint(f);
    b += 0x7fff + ((b >> 16) & 1);
    return (u16)(b >> 16);
}
__device__ inline u32 pack2(float lo, float hi) {
    return (u32)f2bf(lo) | ((u32)f2bf(hi) << 16);
}

// ------------------------------- CSR build ---------------------------------

__global__ __launch_bounds__(256) void k_hist1(const int* __restrict__ dst,
                                               int* __restrict__ hist1,
                                               int E, int NB) {
    __shared__ int h[256];
    int t = threadIdx.x;
    h[t] = 0;
    __syncthreads();
    for (int i = blockIdx.x * 256 * 16 + t; i < min(E, (blockIdx.x + 1) * 256 * 16);
         i += 256)
        atomicAdd(&h[dst[i] >> CSHIFT], 1);
    __syncthreads();
    if (t < NB && h[t]) atomicAdd(&hist1[t], h[t]);
}

__global__ __launch_bounds__(256) void k_scan1(const int* __restrict__ hist1,
                                               int* __restrict__ base1,
                                               int* __restrict__ cur1,
                                               int NB, int E) {
    __shared__ int sc[256];
    int t = threadIdx.x;
    int v = (t < NB) ? hist1[t] : 0;
    sc[t] = v;
    __syncthreads();
    for (int d = 1; d < 256; d <<= 1) {
        int add = (t >= d) ? sc[t - d] : 0;
        __syncthreads();
        sc[t] += add;
        __syncthreads();
    }
    if (t < NB) {
        int excl = sc[t] - v;
        base1[t] = excl;
        cur1[t] = excl;
    }
    if (t == 0) base1[NB] = E;
}

__global__ __launch_bounds__(256) void k_part1(const int* __restrict__ src,
                                               const int* __restrict__ dst,
                                               int* __restrict__ cur1,
                                               u32* __restrict__ bkt,
                                               int E, int NB) {
    __shared__ u32 stage[PCHUNK];
    __shared__ u8 sbin[PCHUNK];
    __shared__ int cnt[256];
    __shared__ int lbase[256];
    __shared__ int lcur[256];
    __shared__ int gb[256];
    int t = threadIdx.x;
    int base = blockIdx.x * PCHUNK;
    int n = min(PCHUNK, E - base);
    cnt[t] = 0;
    __syncthreads();
    for (int i = t; i < n; i += 256) atomicAdd(&cnt[dst[base + i] >> CSHIFT], 1);
    __syncthreads();
    int v = cnt[t];
    lbase[t] = v;
    __syncthreads();
    for (int d = 1; d < 256; d <<= 1) {
        int add = (t >= d) ? lbase[t - d] : 0;
        __syncthreads();
        lbase[t] += add;
        __syncthreads();
    }
    {
        int excl = lbase[t] - v;
        __syncthreads();
        lbase[t] = excl;
        lcur[t] = excl;
        if (t < NB && v) gb[t] = atomicAdd(&cur1[t], v);
    }
    __syncthreads();
    for (int i = t; i < n; i += 256) {
        int d = dst[base + i];
        int s = src[base + i];
        int bin = d >> CSHIFT;
        int p = atomicAdd(&lcur[bin], 1);
        stage[p] = ((u32)s << CSHIFT) | (u32)(d & (CSZ - 1));
        sbin[p] = (u8)bin;
    }
    __syncthreads();
    for (int k = t; k < n; k += 256) {
        int bin = sbin[k];
        bkt[gb[bin] + (k - lbase[bin])] = stage[k];
    }
}

__global__ __launch_bounds__(1024) void k_csr(const u32* __restrict__ bkt,
                                              const int* __restrict__ base1,
                                              int* __restrict__ col,
                                              int* __restrict__ row,
                                              float* __restrict__ dinv,
                                              int N, int E) {
    __shared__ int deg[CSZ];
    __shared__ int cur[CSZ];
    int b = blockIdx.x;
    int t = threadIdx.x;
    int start = base1[b];
    int end = base1[b + 1];
    if (t < CSZ) deg[t] = 0;
    __syncthreads();
    for (int i = start + t; i < end; i += 1024)
        atomicAdd(&deg[bkt[i] & (CSZ - 1)], 1);
    __syncthreads();
    int v = (t < CSZ) ? deg[t] : 0;
    if (t < CSZ) cur[t] = v;
    __syncthreads();
    for (int d = 1; d < CSZ; d <<= 1) {
        int add = (t < CSZ && t >= d) ? cur[t - d] : 0;
        __syncthreads();
        if (t < CSZ) cur[t] += add;
        __syncthreads();
    }
    if (t < CSZ) {
        int excl = cur[t] - v;
        int node = (b << CSHIFT) + t;
        if (node < N) {
            row[node] = start + excl;
            dinv[node] = rsqrtf((float)(v + 1));
        }
        cur[t] = excl;
    }
    __syncthreads();
    for (int i = start + t; i < end; i += 1024) {
        u32 e = bkt[i];
        int p = start + atomicAdd(&cur[e & (CSZ - 1)], 1);
        col[p] = (int)(e >> CSHIFT);
    }
    if (b == 0 && t == 0) row[N] = E;
}

// ------------------------------ weight packing -----------------------------

template <int NCT, int C>
__global__ __launch_bounds__(256) void k_packW(const float* __restrict__ W,
                                               u16* __restrict__ Wpk) {
    int g = blockIdx.x * 256 + threadIdx.x;
    if (g >= NCT * 4 * 512) return;
    int j = g & 7;
    int l = (g >> 3) & 63;
    int f = g >> 9;
    int ct = f % NCT, ks = f / NCT;
    int krow = ks * 32 + ((l >> 4) << 3) + j;
    int wcol = ct * 16 + (l & 15);
    Wpk[g] = (wcol < C) ? f2bf(W[krow * C + wcol]) : (u16)0;
}

// ---------------------------- MFMA GEMM family -----------------------------

// C[r](bf16) = dinv[r] * (A[r] @ W). Wave: 16 rows x NCT*16 cols, LDS-free.
// ATILED: A is Xt[chunk][node][16].  OTILED: C written to Xt layout.
template <bool AFP32, bool ATILED, int NCT, bool OTILED>
__global__ __launch_bounds__(256) void k_gemmN(const void* __restrict__ Av,
                                               const u16* __restrict__ Wpk,
                                               u16* __restrict__ C,
                                               const float* __restrict__ dinv,
                                               int M, int ostride) {
    int tid = threadIdx.x;
    int wv = blockIdx.x * 4 + (tid >> 6);
    int rowbase = wv * 16;
    if (rowbase >= M) return;
    int l = tid & 63;
    int r = l & 15, hi = l >> 4;
    int arow = min(rowbase + r, M - 1);

    f32x4 acc[NCT];
#pragma unroll
    for (int ct = 0; ct < NCT; ++ct) acc[ct] = (f32x4)(0.f);

    const uint4* wp = (const uint4*)Wpk;
#pragma unroll
    for (int ks = 0; ks < 4; ++ks) {
        s16x8 afrag;
        if (AFP32) {
            const float* A = (const float*)Av;
            int abase = arow * 128 + ks * 32 + hi * 8;
            float4 a0 = *(const float4*)&A[abase];
            float4 a1 = *(const float4*)&A[abase + 4];
            uint4 u = make_uint4(pack2(a0.x, a0.y), pack2(a0.z, a0.w),
                                 pack2(a1.x, a1.y), pack2(a1.z, a1.w));
            afrag = *(s16x8*)&u;
        } else if (ATILED) {
            const u16* A = (const u16*)Av;
            int k0 = ks * 32 + hi * 8;
            int ch = k0 >> 4, off = k0 & 15;
            uint4 u = *(const uint4*)&A[((size_t)ch * M + arow) * 16 + off];
            afrag = *(s16x8*)&u;
        } else {
            const u16* A = (const u16*)Av;
            uint4 u = *(const uint4*)&A[(size_t)arow * 128 + ks * 32 + hi * 8];
            afrag = *(s16x8*)&u;
        }
#pragma unroll
        for (int ct = 0; ct < NCT; ++ct) {
            uint4 b = wp[(ks * NCT + ct) * 64 + l];
            s16x8 bfrag = *(s16x8*)&b;
            acc[ct] = __builtin_amdgcn_mfma_f32_16x16x32_bf16(afrag, bfrag, acc[ct], 0, 0, 0);
        }
    }
#pragma unroll
    for (int ct = 0; ct < NCT; ++ct) {
#pragma unroll
        for (int reg = 0; reg < 4; ++reg) {
            int orow = rowbase + 4 * hi + reg;
            int oc = ct * 16 + r;
            if (orow < M && oc < ostride) {
                u16 val = f2bf(dinv[orow] * acc[ct][reg]);
                if (OTILED)
                    C[((size_t)ct * M + orow) * 16 + r] = val;
                else
                    C[(size_t)orow * ostride + oc] = val;
            }
        }
    }
}

// --------------------------- tiled aggregation -----------------------------

// Xt[chunk][node][16] gather; chunk = blockIdx&7 (XCD-affine: slice is
// L2-resident). 4 lanes x 8B per node, 16 nodes/wave, 4-deep unroll.
// nt loads for col (streamed), nt stores for Y. Fused bias+BN+ReLU.
__global__ __launch_bounds__(256) void k_agg128t(const u16* __restrict__ X,
                                                 u16* __restrict__ Y,
                                                 const int* __restrict__ row,
                                                 const int* __restrict__ col,
                                                 const float* __restrict__ dinv,
                                                 const float* __restrict__ bias,
                                                 const float* __restrict__ g,
                                                 const float* __restrict__ be,
                                                 const float* __restrict__ mean,
                                                 const float* __restrict__ var,
                                                 int n) {
    int tid = threadIdx.x;
    int ch = blockIdx.x & 7;
    int nblk = blockIdx.x >> 3;
    int wid = tid >> 6, l = tid & 63;
    int gi = l >> 2, li = l & 3;
    int node = nblk * 64 + wid * 16 + gi;
    bool valid = node < n;
    int nc = valid ? node : (n - 1);
    const u16* Xc = X + (size_t)ch * n * 16;
    int s = row[nc], e = row[nc + 1];
    int fo = li * 4;

    uint2 v = *(const uint2*)&Xc[(size_t)nc * 16 + fo];  // self (pre-scaled)
    float a0 = bflo(v.x), a1 = bfhi(v.x), a2 = bflo(v.y), a3 = bfhi(v.y);
    float b0 = 0, b1 = 0, b2 = 0, b3 = 0;
    float c0 = 0, c1 = 0, c2 = 0, c3 = 0;
    float d0 = 0, d1 = 0, d2 = 0, d3 = 0;
    int j = s;
    for (; j + 4 <= e; j += 4) {
        int e0 = __builtin_nontemporal_load(col + j);
        int e1 = __builtin_nontemporal_load(col + j + 1);
        int e2 = __builtin_nontemporal_load(col + j + 2);
        int e3 = __builtin_nontemporal_load(col + j + 3);
        uint2 x0 = *(const uint2*)&Xc[(size_t)e0 * 16 + fo];
        uint2 x1 = *(const uint2*)&Xc[(size_t)e1 * 16 + fo];
        uint2 x2 = *(const uint2*)&Xc[(size_t)e2 * 16 + fo];
        uint2 x3 = *(const uint2*)&Xc[(size_t)e3 * 16 + fo];
        a0 += bflo(x0.x); a1 += bfhi(x0.x); a2 += bflo(x0.y); a3 += bfhi(x0.y);
        b0 += bflo(x1.x); b1 += bfhi(x1.x); b2 += bflo(x1.y); b3 += bfhi(x1.y);
        c0 += bflo(x2.x); c1 += bfhi(x2.x); c2 += bflo(x2.y); c3 += bfhi(x2.y);
        d0 += bflo(x3.x); d1 += bfhi(x3.x); d2 += bflo(x3.y); d3 += bfhi(x3.y);
    }
    for (; j < e; ++j) {
        int e0 = __builtin_nontemporal_load(col + j);
        uint2 x0 = *(const uint2*)&Xc[(size_t)e0 * 16 + fo];
        a0 += bflo(x0.x); a1 += bfhi(x0.x); a2 += bflo(x0.y); a3 += bfhi(x0.y);
    }
    float dv = dinv[nc];
    float s0 = dv * ((a0 + b0) + (c0 + d0));
    float s1 = dv * ((a1 + b1) + (c1 + d1));
    float s2 = dv * ((a2 + b2) + (c2 + d2));
    float s3 = dv * ((a3 + b3) + (c3 + d3));
    int pidx = ch * 4 + li;   // float4 index into 128-feat param vectors
    float4 g4 = ((const float4*)g)[pidx];
    float4 be4 = ((const float4*)be)[pidx];
    float4 m4 = ((const float4*)mean)[pidx];
    float4 v4 = ((const float4*)var)[pidx];
    float4 bi4 = ((const float4*)bias)[pidx];
    float sc0 = g4.x * rsqrtf(v4.x + 1e-5f);
    float sc1 = g4.y * rsqrtf(v4.y + 1e-5f);
    float sc2 = g4.z * rsqrtf(v4.z + 1e-5f);
    float sc3 = g4.w * rsqrtf(v4.w + 1e-5f);
    float y0 = fmaxf(fmaf(sc0, s0, fmaf(sc0, bi4.x - m4.x, be4.x)), 0.f);
    float y1 = fmaxf(fmaf(sc1, s1, fmaf(sc1, bi4.y - m4.y, be4.y)), 0.f);
    float y2 = fmaxf(fmaf(sc2, s2, fmaf(sc2, bi4.z - m4.z, be4.z)), 0.f);
    float y3 = fmaxf(fmaf(sc3, s3, fmaf(sc3, bi4.w - m4.w, be4.w)), 0.f);
    if (valid) {
        u32x2 o;
        o.x = pack2(y0, y1);
        o.y = pack2(y2, y3);
        __builtin_nontemporal_store(o, (u32x2*)&Y[((size_t)ch * n + node) * 16 + fo]);
    }
}

// ------------------------------ final agg40 --------------------------------

__global__ __launch_bounds__(256) void k_agg40(const u16* __restrict__ X,
                                               float* __restrict__ out,
                                               const int* __restrict__ row,
                                               const int* __restrict__ col,
                                               const float* __restrict__ dinv,
                                               const float* __restrict__ b2,
                                               int n) {
    int tid = threadIdx.x;
    int wid = tid >> 6, lane = tid & 63;
    int half = lane >> 5, l5 = lane & 31;
    int node = (blockIdx.x * 4 + wid) * 2 + half;
    bool valid = node < n;
    int nc = valid ? node : (n - 1);
    bool active = l5 < 20;
    const u32* xp = (const u32*)X;
    int s = row[nc], e = row[nc + 1];
    int li = min(l5, 19);
    float a0 = 0, a1 = 0, b0 = 0, b1 = 0, c0 = 0, c1 = 0, d0 = 0, d1 = 0;
    {
        u32 v = xp[(size_t)nc * 20 + li];
        a0 = bflo(v); a1 = bfhi(v);
    }
    int j = s;
    for (; j + 8 <= e; j += 8) {
        int e0 = col[j], e1 = col[j+1], e2 = col[j+2], e3 = col[j+3];
        int e4 = col[j+4], e5 = col[j+5], e6 = col[j+6], e7 = col[j+7];
        u32 x0 = xp[(size_t)e0 * 20 + li];
        u32 x1 = xp[(size_t)e1 * 20 + li];
        u32 x2 = xp[(size_t)e2 * 20 + li];
        u32 x3 = xp[(size_t)e3 * 20 + li];
        u32 x4 = xp[(size_t)e4 * 20 + li];
        u32 x5 = xp[(size_t)e5 * 20 + li];
        u32 x6 = xp[(size_t)e6 * 20 + li];
        u32 x7 = xp[(size_t)e7 * 20 + li];
        a0 += bflo(x0); a1 += bfhi(x0);
        b0 += bflo(x1); b1 += bfhi(x1);
        c0 += bflo(x2); c1 += bfhi(x2);
        d0 += bflo(x3); d1 += bfhi(x3);
        a0 += bflo(x4); a1 += bfhi(x4);
        b0 += bflo(x5); b1 += bfhi(x5);
        c0 += bflo(x6); c1 += bfhi(x6);
        d0 += bflo(x7); d1 += bfhi(x7);
    }
    for (; j + 2 <= e; j += 2) {
        int e0 = col[j], e1 = col[j+1];
        u32 x0 = xp[(size_t)e0 * 20 + li];
        u32 x1 = xp[(size_t)e1 * 20 + li];
        a0 += bflo(x0); a1 += bfhi(x0);
        b0 += bflo(x1); b1 += bfhi(x1);
    }
    if (j < e) {
        u32 x0 = xp[(size_t)col[j] * 20 + li];
        c0 += bflo(x0); c1 += bfhi(x0);
    }
    float dv = dinv[nc];
    float ylo = -INFINITY, yhi = -INFINITY;
    if (active) {
        float2 bb = ((const float2*)b2)[l5];
        ylo = fmaf(dv, (a0 + b0) + (c0 + d0), bb.x);
        yhi = fmaf(dv, (a1 + b1) + (c1 + d1), bb.y);
    }
    float m = fmaxf(ylo, yhi);
#pragma unroll
    for (int d = 16; d; d >>= 1) m = fmaxf(m, __shfl_xor(m, d));
    float ex = active ? (__expf(ylo - m) + __expf(yhi - m)) : 0.f;
#pragma unroll
    for (int d = 16; d; d >>= 1) ex += __shfl_xor(ex, d);
    if (valid && active) {
        float lse = m + __logf(ex);
        ((float2*)out)[(size_t)node * 20 + l5] = make_float2(ylo - lse, yhi - lse);
    }
}

// --------------------------------- launch ----------------------------------

extern "C" void kernel_launch(void* const* d_in, const int* in_sizes, int n_in,
                              void* d_out, int out_size, void* d_ws, size_t ws_size,
                              hipStream_t stream) {
    const float* x   = (const float*)d_in[0];
    const int*   ei  = (const int*)d_in[1];
    const float* W0  = (const float*)d_in[2];
    const float* b0  = (const float*)d_in[3];
    const float* W1  = (const float*)d_in[4];
    const float* b1  = (const float*)d_in[5];
    const float* W2  = (const float*)d_in[6];
    const float* b2  = (const float*)d_in[7];
    const float* g0  = (const float*)d_in[8];
    const float* be0 = (const float*)d_in[9];
    const float* m0  = (const float*)d_in[10];
    const float* v0  = (const float*)d_in[11];
    const float* g1  = (const float*)d_in[12];
    const float* be1 = (const float*)d_in[13];
    const float* m1  = (const float*)d_in[14];
    const float* v1  = (const float*)d_in[15];
    float* out = (float*)d_out;

    int N = in_sizes[0] / 128;
    int E = in_sizes[1] / 2;
    const int* src = ei;
    const int* dst = ei + E;

    int NB = (N + CSZ - 1) / CSZ;

    char* ws = (char*)d_ws;
    size_t off = 0;
    auto alloc = [&](size_t bytes) -> char* {
        char* p = ws + off;
        off += (bytes + 255) & ~(size_t)255;
        return p;
    };
    u16*   XsA   = (u16*)alloc((size_t)N * 128 * 2);   // tiled [8][N][16]
    u16*   XsB   = (u16*)alloc((size_t)N * 128 * 2);   // tiled [8][N][16]
    u16*   bufC  = (u16*)alloc((size_t)N * 40 * 2);    // row-major
    int*   col   = (int*)alloc((size_t)E * 4 + 64);
    int*   row   = (int*)alloc((size_t)(N + 1) * 4);
    float* dinv  = (float*)alloc((size_t)N * 4);
    int*   hist1 = (int*)alloc((size_t)(NB + 1) * 4);
    int*   base1 = (int*)alloc((size_t)(NB + 1) * 4);
    int*   cur1  = (int*)alloc((size_t)(NB + 1) * 4);
    u16*   Wpk0  = (u16*)alloc(128 * 128 * 2);
    u16*   Wpk1  = (u16*)alloc(128 * 128 * 2);
    u16*   Wpk2  = (u16*)alloc(128 * 48 * 2);
    u32*   bkt   = (u32*)XsA;  // alias: bkt dead before gemm0 writes XsA

    hipError_t _e = hipMemsetAsync(hist1, 0, (size_t)(NB + 1) * 4, stream);
    (void)_e;
    k_hist1<<<(E + 4095) / 4096, 256, 0, stream>>>(dst, hist1, E, NB);
    k_scan1<<<1, 256, 0, stream>>>(hist1, base1, cur1, NB, E);
    k_part1<<<(E + PCHUNK - 1) / PCHUNK, 256, 0, stream>>>(src, dst, cur1, bkt, E, NB);
    k_csr<<<NB, 1024, 0, stream>>>(bkt, base1, col, row, dinv, N, E);
    k_packW<8, 128><<<64, 256, 0, stream>>>(W0, Wpk0);
    k_packW<8, 128><<<64, 256, 0, stream>>>(W1, Wpk1);
    k_packW<3, 40><<<24, 256, 0, stream>>>(W2, Wpk2);

    int gemmGrid = (N + 63) / 64;
    int aggGrid = 8 * ((N + 63) / 64);
    k_gemmN<true, false, 8, true><<<gemmGrid, 256, 0, stream>>>(x, Wpk0, XsA, dinv, N, 128);
    k_agg128t<<<aggGrid, 256, 0, stream>>>(XsA, XsB, row, col, dinv, b0, g0, be0, m0, v0, N);
    k_gemmN<false, true, 8, true><<<gemmGrid, 256, 0, stream>>>(XsB, Wpk1, XsA, dinv, N, 128);
    k_agg128t<<<aggGrid, 256, 0, stream>>>(XsA, XsB, row, col, dinv, b1, g1, be1, m1, v1, N);
    k_gemmN<false, true, 3, false><<<gemmGrid, 256, 0, stream>>>(XsB, Wpk2, bufC, dinv, N, 40);
    k_agg40<<<(N + 7) / 8, 256, 0, stream>>>(bufC, out, row, col, dinv, b2, N);
}

// Round 14
// 277.767 us; speedup vs baseline: 1.5966x; 1.5966x over previous
//
#include <hip/hip_runtime.h>
#include <math.h>

// ---------------------------------------------------------------------------
// GCN 3-layer inference. bf16 data path, fp32 accumulation.  (R11 structure)
//   CSR build: LDS-multisplit radix partition (PCHUNK=4096, 1024-thr k_csr)
//   k_gemmN<AFP32,NCT>: MFMA 16x16x32 bf16, LDS-free, per-wave 16xNCT*16 tile
//   k_agg128: pure gather-sum + BN+ReLU. Measured fabric roofline: 188MB
//             compulsory L2-fill (8 XCD x 25.6MB, random graph) at ~3.4 TB/s.
//   k_agg40: bf16 gather + bias + log_softmax, 4 nodes/wave (10 lanes x 8B)
// Pipeline: gemm0(x@W0)->XsA; agg128->XsB; gemm1->XsA; agg128->XsB;
//           gemm2(W2,NCT=3)->bufC; agg40->out
// agg identity: out[n] = dinv[n]*( Xs[n] + sum_e Xs[col] ),  Xs = dinv.*(A@W)
// ---------------------------------------------------------------------------

#define CSHIFT 9
#define CSZ 512
#define PCHUNK 4096

typedef unsigned short u16;
typedef unsigned int u32;
typedef unsigned char u8;
typedef float f32x4 __attribute__((ext_vector_type(4)));
typedef short s16x8 __attribute__((ext_vector_type(8)));

__device__ inline float bflo(u32 u) { return __uint_as_float(u << 16); }
__device__ inline float bfhi(u32 u) { return __uint_as_float(u & 0xffff0000u); }
__device__ inline u16 f2bf(float f) {  // RNE
    u32 b = __float_as_uint(f);
    b += 0x7fff + ((b >> 16) & 1);
    return (u16)(b >> 16);
}
__device__ inline u32 pack2(float lo, float hi) {
    return (u32)f2bf(lo) | ((u32)f2bf(hi) << 16);
}

// ------------------------------- CSR build ---------------------------------

__global__ __launch_bounds__(256) void k_hist1(const int* __restrict__ dst,
                                               int* __restrict__ hist1,
                                               int E, int NB) {
    __shared__ int h[256];
    int t = threadIdx.x;
    h[t] = 0;
    __syncthreads();
    for (int i = blockIdx.x * 256 * 16 + t; i < min(E, (blockIdx.x + 1) * 256 * 16);
         i += 256)
        atomicAdd(&h[dst[i] >> CSHIFT], 1);
    __syncthreads();
    if (t < NB && h[t]) atomicAdd(&hist1[t], h[t]);
}

__global__ __launch_bounds__(256) void k_scan1(const int* __restrict__ hist1,
                                               int* __restrict__ base1,
                                               int* __restrict__ cur1,
                                               int NB, int E) {
    __shared__ int sc[256];
    int t = threadIdx.x;
    int v = (t < NB) ? hist1[t] : 0;
    sc[t] = v;
    __syncthreads();
    for (int d = 1; d < 256; d <<= 1) {
        int add = (t >= d) ? sc[t - d] : 0;
        __syncthreads();
        sc[t] += add;
        __syncthreads();
    }
    if (t < NB) {
        int excl = sc[t] - v;
        base1[t] = excl;
        cur1[t] = excl;
    }
    if (t == 0) base1[NB] = E;
}

__global__ __launch_bounds__(256) void k_part1(const int* __restrict__ src,
                                               const int* __restrict__ dst,
                                               int* __restrict__ cur1,
                                               u32* __restrict__ bkt,
                                               int E, int NB) {
    __shared__ u32 stage[PCHUNK];
    __shared__ u8 sbin[PCHUNK];
    __shared__ int cnt[256];
    __shared__ int lbase[256];
    __shared__ int lcur[256];
    __shared__ int gb[256];
    int t = threadIdx.x;
    int base = blockIdx.x * PCHUNK;
    int n = min(PCHUNK, E - base);
    cnt[t] = 0;
    __syncthreads();
    for (int i = t; i < n; i += 256) atomicAdd(&cnt[dst[base + i] >> CSHIFT], 1);
    __syncthreads();
    int v = cnt[t];
    lbase[t] = v;
    __syncthreads();
    for (int d = 1; d < 256; d <<= 1) {
        int add = (t >= d) ? lbase[t - d] : 0;
        __syncthreads();
        lbase[t] += add;
        __syncthreads();
    }
    {
        int excl = lbase[t] - v;
        __syncthreads();
        lbase[t] = excl;
        lcur[t] = excl;
        if (t < NB && v) gb[t] = atomicAdd(&cur1[t], v);
    }
    __syncthreads();
    for (int i = t; i < n; i += 256) {
        int d = dst[base + i];
        int s = src[base + i];
        int bin = d >> CSHIFT;
        int p = atomicAdd(&lcur[bin], 1);
        stage[p] = ((u32)s << CSHIFT) | (u32)(d & (CSZ - 1));
        sbin[p] = (u8)bin;
    }
    __syncthreads();
    for (int k = t; k < n; k += 256) {
        int bin = sbin[k];
        bkt[gb[bin] + (k - lbase[bin])] = stage[k];
    }
}

__global__ __launch_bounds__(1024) void k_csr(const u32* __restrict__ bkt,
                                              const int* __restrict__ base1,
                                              int* __restrict__ col,
                                              int* __restrict__ row,
                                              float* __restrict__ dinv,
                                              int N, int E) {
    __shared__ int deg[CSZ];
    __shared__ int cur[CSZ];
    int b = blockIdx.x;
    int t = threadIdx.x;
    int start = base1[b];
    int end = base1[b + 1];
    if (t < CSZ) deg[t] = 0;
    __syncthreads();
    for (int i = start + t; i < end; i += 1024)
        atomicAdd(&deg[bkt[i] & (CSZ - 1)], 1);
    __syncthreads();
    int v = (t < CSZ) ? deg[t] : 0;
    if (t < CSZ) cur[t] = v;
    __syncthreads();
    for (int d = 1; d < CSZ; d <<= 1) {
        int add = (t < CSZ && t >= d) ? cur[t - d] : 0;
        __syncthreads();
        if (t < CSZ) cur[t] += add;
        __syncthreads();
    }
    if (t < CSZ) {
        int excl = cur[t] - v;
        int node = (b << CSHIFT) + t;
        if (node < N) {
            row[node] = start + excl;
            dinv[node] = rsqrtf((float)(v + 1));
        }
        cur[t] = excl;
    }
    __syncthreads();
    for (int i = start + t; i < end; i += 1024) {
        u32 e = bkt[i];
        int p = start + atomicAdd(&cur[e & (CSZ - 1)], 1);
        col[p] = (int)(e >> CSHIFT);
    }
    if (b == 0 && t == 0) row[N] = E;
}

// ------------------------------ weight packing -----------------------------

template <int NCT, int C>
__device__ inline void packW_elem(const float* __restrict__ W,
                                  u16* __restrict__ Wpk, int g) {
    int j = g & 7;
    int l = (g >> 3) & 63;
    int f = g >> 9;
    int ct = f % NCT, ks = f / NCT;
    int krow = ks * 32 + ((l >> 4) << 3) + j;
    int wcol = ct * 16 + (l & 15);
    Wpk[g] = (wcol < C) ? f2bf(W[krow * C + wcol]) : (u16)0;
}

// single launch packs W0, W1 (NCT=8,C=128) and W2 (NCT=3,C=40)
__global__ __launch_bounds__(256) void k_packAll(const float* __restrict__ W0,
                                                 const float* __restrict__ W1,
                                                 const float* __restrict__ W2,
                                                 u16* __restrict__ Wpk0,
                                                 u16* __restrict__ Wpk1,
                                                 u16* __restrict__ Wpk2) {
    int b = blockIdx.x;
    int t = threadIdx.x;
    if (b < 64) {
        packW_elem<8, 128>(W0, Wpk0, b * 256 + t);
    } else if (b < 128) {
        packW_elem<8, 128>(W1, Wpk1, (b - 64) * 256 + t);
    } else {
        int g = (b - 128) * 256 + t;
        if (g < 12 * 512) packW_elem<3, 40>(W2, Wpk2, g);
    }
}

// ---------------------------- MFMA GEMM family -----------------------------

// C[r](bf16) = dinv[r] * (A[r] @ W). Wave: 16 rows x NCT*16 cols, LDS-free.
template <bool AFP32, int NCT>
__global__ __launch_bounds__(256) void k_gemmN(const void* __restrict__ Av,
                                               const u16* __restrict__ Wpk,
                                               u16* __restrict__ C,
                                               const float* __restrict__ dinv,
                                               int M, int ostride) {
    int tid = threadIdx.x;
    int wv = blockIdx.x * 4 + (tid >> 6);
    int rowbase = wv * 16;
    if (rowbase >= M) return;
    int l = tid & 63;
    int r = l & 15, hi = l >> 4;

    f32x4 acc[NCT];
#pragma unroll
    for (int ct = 0; ct < NCT; ++ct) acc[ct] = (f32x4)(0.f);

    const uint4* wp = (const uint4*)Wpk;
#pragma unroll
    for (int ks = 0; ks < 4; ++ks) {
        s16x8 afrag;
        int abase = (min(rowbase + r, M - 1)) * 128 + ks * 32 + hi * 8;
        if (AFP32) {
            const float* A = (const float*)Av;
            float4 a0 = *(const float4*)&A[abase];
            float4 a1 = *(const float4*)&A[abase + 4];
            uint4 u = make_uint4(pack2(a0.x, a0.y), pack2(a0.z, a0.w),
                                 pack2(a1.x, a1.y), pack2(a1.z, a1.w));
            afrag = *(s16x8*)&u;
        } else {
            const u16* A = (const u16*)Av;
            uint4 u = *(const uint4*)&A[abase];
            afrag = *(s16x8*)&u;
        }
#pragma unroll
        for (int ct = 0; ct < NCT; ++ct) {
            uint4 b = wp[(ks * NCT + ct) * 64 + l];
            s16x8 bfrag = *(s16x8*)&b;
            acc[ct] = __builtin_amdgcn_mfma_f32_16x16x32_bf16(afrag, bfrag, acc[ct], 0, 0, 0);
        }
    }
#pragma unroll
    for (int ct = 0; ct < NCT; ++ct) {
#pragma unroll
        for (int reg = 0; reg < 4; ++reg) {
            int orow = rowbase + 4 * hi + reg;
            int oc = ct * 16 + r;
            if (orow < M && oc < ostride)
                C[(size_t)orow * ostride + oc] = f2bf(dinv[orow] * acc[ct][reg]);
        }
    }
}

// ------------------------------ aggregation --------------------------------

// d=128 bf16 gather-sum; 2 nodes/wave; 8/2/1 unrolled; fused bias+BN+ReLU.
// At the cross-XCD fabric roofline (~3.4 TB/s effective, 188MB compulsory).
__global__ __launch_bounds__(256) void k_agg128(const u16* __restrict__ X,
                                                u16* __restrict__ Y,
                                                const int* __restrict__ row,
                                                const int* __restrict__ col,
                                                const float* __restrict__ dinv,
                                                const float* __restrict__ bias,
                                                const float* __restrict__ g,
                                                const float* __restrict__ be,
                                                const float* __restrict__ mean,
                                                const float* __restrict__ var,
                                                int n) {
    int tid = threadIdx.x;
    int wid = tid >> 6, lane = tid & 63;
    int half = lane >> 5, l5 = lane & 31;
    int node = (blockIdx.x * 4 + wid) * 2 + half;
    bool valid = node < n;
    int nc = valid ? node : (n - 1);
    const uint2* xp = (const uint2*)X;
    int s = row[nc], e = row[nc + 1];
    uint2 v = xp[(size_t)nc * 32 + l5];
    float a0 = bflo(v.x), a1 = bfhi(v.x), a2 = bflo(v.y), a3 = bfhi(v.y);
    float b0 = 0, b1 = 0, b2 = 0, b3 = 0;
    float c0 = 0, c1 = 0, c2 = 0, c3 = 0;
    float d0 = 0, d1 = 0, d2 = 0, d3 = 0;
    int j = s;
    for (; j + 8 <= e; j += 8) {
        int e0 = col[j], e1 = col[j+1], e2 = col[j+2], e3 = col[j+3];
        int e4 = col[j+4], e5 = col[j+5], e6 = col[j+6], e7 = col[j+7];
        uint2 x0 = xp[(size_t)e0 * 32 + l5];
        uint2 x1 = xp[(size_t)e1 * 32 + l5];
        uint2 x2 = xp[(size_t)e2 * 32 + l5];
        uint2 x3 = xp[(size_t)e3 * 32 + l5];
        uint2 x4 = xp[(size_t)e4 * 32 + l5];
        uint2 x5 = xp[(size_t)e5 * 32 + l5];
        uint2 x6 = xp[(size_t)e6 * 32 + l5];
        uint2 x7 = xp[(size_t)e7 * 32 + l5];
        a0 += bflo(x0.x); a1 += bfhi(x0.x); a2 += bflo(x0.y); a3 += bfhi(x0.y);
        b0 += bflo(x1.x); b1 += bfhi(x1.x); b2 += bflo(x1.y); b3 += bfhi(x1.y);
        c0 += bflo(x2.x); c1 += bfhi(x2.x); c2 += bflo(x2.y); c3 += bfhi(x2.y);
        d0 += bflo(x3.x); d1 += bfhi(x3.x); d2 += bflo(x3.y); d3 += bfhi(x3.y);
        a0 += bflo(x4.x); a1 += bfhi(x4.x); a2 += bflo(x4.y); a3 += bfhi(x4.y);
        b0 += bflo(x5.x); b1 += bfhi(x5.x); b2 += bflo(x5.y); b3 += bfhi(x5.y);
        c0 += bflo(x6.x); c1 += bfhi(x6.x); c2 += bflo(x6.y); c3 += bfhi(x6.y);
        d0 += bflo(x7.x); d1 += bfhi(x7.x); d2 += bflo(x7.y); d3 += bfhi(x7.y);
    }
    for (; j + 2 <= e; j += 2) {
        int e0 = col[j], e1 = col[j+1];
        uint2 x0 = xp[(size_t)e0 * 32 + l5];
        uint2 x1 = xp[(size_t)e1 * 32 + l5];
        a0 += bflo(x0.x); a1 += bfhi(x0.x); a2 += bflo(x0.y); a3 += bfhi(x0.y);
        b0 += bflo(x1.x); b1 += bfhi(x1.x); b2 += bflo(x1.y); b3 += bfhi(x1.y);
    }
    if (j < e) {
        uint2 x0 = xp[(size_t)col[j] * 32 + l5];
        c0 += bflo(x0.x); c1 += bfhi(x0.x); c2 += bflo(x0.y); c3 += bfhi(x0.y);
    }
    float dv = dinv[nc];
    float s0 = dv * ((a0 + b0) + (c0 + d0));
    float s1 = dv * ((a1 + b1) + (c1 + d1));
    float s2 = dv * ((a2 + b2) + (c2 + d2));
    float s3 = dv * ((a3 + b3) + (c3 + d3));
    float4 g4 = ((const float4*)g)[l5];
    float4 be4 = ((const float4*)be)[l5];
    float4 m4 = ((const float4*)mean)[l5];
    float4 v4 = ((const float4*)var)[l5];
    float4 bi4 = ((const float4*)bias)[l5];
    float sc0 = g4.x * rsqrtf(v4.x + 1e-5f);
    float sc1 = g4.y * rsqrtf(v4.y + 1e-5f);
    float sc2 = g4.z * rsqrtf(v4.z + 1e-5f);
    float sc3 = g4.w * rsqrtf(v4.w + 1e-5f);
    float y0 = fmaxf(fmaf(sc0, s0, fmaf(sc0, bi4.x - m4.x, be4.x)), 0.f);
    float y1 = fmaxf(fmaf(sc1, s1, fmaf(sc1, bi4.y - m4.y, be4.y)), 0.f);
    float y2 = fmaxf(fmaf(sc2, s2, fmaf(sc2, bi4.z - m4.z, be4.z)), 0.f);
    float y3 = fmaxf(fmaf(sc3, s3, fmaf(sc3, bi4.w - m4.w, be4.w)), 0.f);
    if (valid) {
        uint2 o;
        o.x = pack2(y0, y1);
        o.y = pack2(y2, y3);
        ((uint2*)Y)[(size_t)node * 32 + l5] = o;
    }
}

// d=40 bf16 gather-sum + bias + log_softmax; 4 nodes/wave (16-lane groups,
// 10 active lanes x uint2 = 8B): 320B gathered per load instruction.
__global__ __launch_bounds__(256) void k_agg40(const u16* __restrict__ X,
                                               float* __restrict__ out,
                                               const int* __restrict__ row,
                                               const int* __restrict__ col,
                                               const float* __restrict__ dinv,
                                               const float* __restrict__ b2,
                                               int n) {
    int tid = threadIdx.x;
    int wid = tid >> 6, lane = tid & 63;
    int grp = lane >> 4, li = lane & 15;
    int node = (blockIdx.x * 4 + wid) * 4 + grp;
    bool valid = node < n;
    int nc = valid ? node : (n - 1);
    bool active = li < 10;
    int liw = min(li, 9);
    const uint2* xp = (const uint2*)X;   // 10 uint2 per 40-col row
    int s = row[nc], e = row[nc + 1];

    uint2 v = xp[(size_t)nc * 10 + liw];  // self (pre-scaled)
    float a0 = bflo(v.x), a1 = bfhi(v.x), a2 = bflo(v.y), a3 = bfhi(v.y);
    float b0 = 0, b1 = 0, b2_ = 0, b3 = 0;
    float c0 = 0, c1 = 0, c2 = 0, c3 = 0;
    float d0 = 0, d1 = 0, d2 = 0, d3 = 0;
    int j = s;
    for (; j + 8 <= e; j += 8) {
        int e0 = col[j], e1 = col[j+1], e2 = col[j+2], e3 = col[j+3];
        int e4 = col[j+4], e5 = col[j+5], e6 = col[j+6], e7 = col[j+7];
        uint2 x0 = xp[(size_t)e0 * 10 + liw];
        uint2 x1 = xp[(size_t)e1 * 10 + liw];
        uint2 x2 = xp[(size_t)e2 * 10 + liw];
        uint2 x3 = xp[(size_t)e3 * 10 + liw];
        uint2 x4 = xp[(size_t)e4 * 10 + liw];
        uint2 x5 = xp[(size_t)e5 * 10 + liw];
        uint2 x6 = xp[(size_t)e6 * 10 + liw];
        uint2 x7 = xp[(size_t)e7 * 10 + liw];
        a0 += bflo(x0.x); a1 += bfhi(x0.x); a2 += bflo(x0.y); a3 += bfhi(x0.y);
        b0 += bflo(x1.x); b1 += bfhi(x1.x); b2_ += bflo(x1.y); b3 += bfhi(x1.y);
        c0 += bflo(x2.x); c1 += bfhi(x2.x); c2 += bflo(x2.y); c3 += bfhi(x2.y);
        d0 += bflo(x3.x); d1 += bfhi(x3.x); d2 += bflo(x3.y); d3 += bfhi(x3.y);
        a0 += bflo(x4.x); a1 += bfhi(x4.x); a2 += bflo(x4.y); a3 += bfhi(x4.y);
        b0 += bflo(x5.x); b1 += bfhi(x5.x); b2_ += bflo(x5.y); b3 += bfhi(x5.y);
        c0 += bflo(x6.x); c1 += bfhi(x6.x); c2 += bflo(x6.y); c3 += bfhi(x6.y);
        d0 += bflo(x7.x); d1 += bfhi(x7.x); d2 += bflo(x7.y); d3 += bfhi(x7.y);
    }
    for (; j + 2 <= e; j += 2) {
        int e0 = col[j], e1 = col[j+1];
        uint2 x0 = xp[(size_t)e0 * 10 + liw];
        uint2 x1 = xp[(size_t)e1 * 10 + liw];
        a0 += bflo(x0.x); a1 += bfhi(x0.x); a2 += bflo(x0.y); a3 += bfhi(x0.y);
        b0 += bflo(x1.x); b1 += bfhi(x1.x); b2_ += bflo(x1.y); b3 += bfhi(x1.y);
    }
    if (j < e) {
        uint2 x0 = xp[(size_t)col[j] * 10 + liw];
        c0 += bflo(x0.x); c1 += bfhi(x0.x); c2 += bflo(x0.y); c3 += bfhi(x0.y);
    }
    float dv = dinv[nc];
    float y0 = -INFINITY, y1 = -INFINITY, y2 = -INFINITY, y3 = -INFINITY;
    if (active) {
        float4 bb = ((const float4*)b2)[liw];
        y0 = fmaf(dv, (a0 + b0) + (c0 + d0), bb.x);
        y1 = fmaf(dv, (a1 + b1) + (c1 + d1), bb.y);
        y2 = fmaf(dv, (a2 + b2_) + (c2 + d2), bb.z);
        y3 = fmaf(dv, (a3 + b3) + (c3 + d3), bb.w);
    }
    float m = fmaxf(fmaxf(y0, y1), fmaxf(y2, y3));
#pragma unroll
    for (int d = 8; d; d >>= 1) m = fmaxf(m, __shfl_xor(m, d));
    float ex = 0.f;
    if (active)
        ex = (__expf(y0 - m) + __expf(y1 - m)) + (__expf(y2 - m) + __expf(y3 - m));
#pragma unroll
    for (int d = 8; d; d >>= 1) ex += __shfl_xor(ex, d);
    if (valid && active) {
        float lse = m + __logf(ex);
        ((float4*)out)[(size_t)node * 10 + li] =
            make_float4(y0 - lse, y1 - lse, y2 - lse, y3 - lse);
    }
}

// --------------------------------- launch ----------------------------------

extern "C" void kernel_launch(void* const* d_in, const int* in_sizes, int n_in,
                              void* d_out, int out_size, void* d_ws, size_t ws_size,
                              hipStream_t stream) {
    const float* x   = (const float*)d_in[0];
    const int*   ei  = (const int*)d_in[1];
    const float* W0  = (const float*)d_in[2];
    const float* b0  = (const float*)d_in[3];
    const float* W1  = (const float*)d_in[4];
    const float* b1  = (const float*)d_in[5];
    const float* W2  = (const float*)d_in[6];
    const float* b2  = (const float*)d_in[7];
    const float* g0  = (const float*)d_in[8];
    const float* be0 = (const float*)d_in[9];
    const float* m0  = (const float*)d_in[10];
    const float* v0  = (const float*)d_in[11];
    const float* g1  = (const float*)d_in[12];
    const float* be1 = (const float*)d_in[13];
    const float* m1  = (const float*)d_in[14];
    const float* v1  = (const float*)d_in[15];
    float* out = (float*)d_out;

    int N = in_sizes[0] / 128;
    int E = in_sizes[1] / 2;
    const int* src = ei;
    const int* dst = ei + E;

    int NB = (N + CSZ - 1) / CSZ;

    char* ws = (char*)d_ws;
    size_t off = 0;
    auto alloc = [&](size_t bytes) -> char* {
        char* p = ws + off;
        off += (bytes + 255) & ~(size_t)255;
        return p;
    };
    u16*   XsA   = (u16*)alloc((size_t)N * 128 * 2);
    u16*   XsB   = (u16*)alloc((size_t)N * 128 * 2);
    u16*   bufC  = (u16*)alloc((size_t)N * 40 * 2);
    int*   col   = (int*)alloc((size_t)E * 4 + 64);
    int*   row   = (int*)alloc((size_t)(N + 1) * 4);
    float* dinv  = (float*)alloc((size_t)N * 4);
    int*   hist1 = (int*)alloc((size_t)(NB + 1) * 4);
    int*   base1 = (int*)alloc((size_t)(NB + 1) * 4);
    int*   cur1  = (int*)alloc((size_t)(NB + 1) * 4);
    u16*   Wpk0  = (u16*)alloc(128 * 128 * 2);
    u16*   Wpk1  = (u16*)alloc(128 * 128 * 2);
    u16*   Wpk2  = (u16*)alloc(128 * 48 * 2);
    u32*   bkt   = (u32*)XsA;  // alias: bkt dead before gemm0 writes XsA

    hipError_t _e = hipMemsetAsync(hist1, 0, (size_t)(NB + 1) * 4, stream);
    (void)_e;
    k_hist1<<<(E + 4095) / 4096, 256, 0, stream>>>(dst, hist1, E, NB);
    k_scan1<<<1, 256, 0, stream>>>(hist1, base1, cur1, NB, E);
    k_part1<<<(E + PCHUNK - 1) / PCHUNK, 256, 0, stream>>>(src, dst, cur1, bkt, E, NB);
    k_csr<<<NB, 1024, 0, stream>>>(bkt, base1, col, row, dinv, N, E);
    k_packAll<<<152, 256, 0, stream>>>(W0, W1, W2, Wpk0, Wpk1, Wpk2);

    int gemmGrid = ((N + 15) / 16 + 3) / 4;
    k_gemmN<true, 8><<<gemmGrid, 256, 0, stream>>>(x, Wpk0, XsA, dinv, N, 128);
    k_agg128<<<(N + 7) / 8, 256, 0, stream>>>(XsA, XsB, row, col, dinv, b0, g0, be0, m0, v0, N);
    k_gemmN<false, 8><<<gemmGrid, 256, 0, stream>>>(XsB, Wpk1, XsA, dinv, N, 128);
    k_agg128<<<(N + 7) / 8, 256, 0, stream>>>(XsA, XsB, row, col, dinv, b1, g1, be1, m1, v1, N);
    k_gemmN<false, 3><<<gemmGrid, 256, 0, stream>>>(XsB, Wpk2, bufC, dinv, N, 40);
    k_agg40<<<(N + 15) / 16, 256, 0, stream>>>(bufC, out, row, col, dinv, b2, N);
}